// Round 7
// baseline (378.720 us; speedup 1.0000x reference)
//
#include <hip/hip_runtime.h>
#include <stdint.h>

// ---------------------------------------------------------------------------
// StyleGAN2 block: upsample2x -> modconv3x3 -> noise+lrelu -> modconv3x3 ->
// noise+lrelu -> to_rgb(1x1, no demod) + upsampled rgb skip.
// v7: conv K-loop = ONE barrier per kb (was 3):
//   - B: all 4 rows (full 66 px incl. pad cols) staged per kb, double-buffered
//     LDS (33.8KB); no pad-column clamp VALU (k_zero zeroes pad cols).
//   - A: direct global->VGPR; Wt re-laid out [kb][ky][q][co][kx][8] so the 12
//     frags of a (kb,ky) chunk are immediate offsets off ONE base pointer.
//   - 144 MFMAs between barriers; drain+VALU amortized 3x.
// ---------------------------------------------------------------------------

#define BATCH 4
#define CH 512
#define NPP 4356        // 66*66
#define HOUT_OFF 49152  // rgb_out elements before h in d_out

static constexpr double G_GAIN = 1.3867504905630728;  // sqrt(2/(1+0.04))
static constexpr float CONV_SCALE_F = (float)(G_GAIN / 67.88225099390857);  // /sqrt(512*9)
static constexpr float MS_SCALE_F = 0.044194173824159216f;                  // sqrt(2/1024)
static constexpr float RGB_SCALE_F = (float)(G_GAIN * 1.4142135623730951 / 22.693611435820433); // *sqrt(2/515)

typedef __attribute__((ext_vector_type(8))) short short8;
typedef __attribute__((ext_vector_type(4))) float floatx4;

// ---------------- workspace layout (bytes) ----------------
#define OFF_FLAG   0
#define OFF_S0     256
#define OFF_S1     (OFF_S0 + 8192)
#define OFF_SR     (OFF_S1 + 8192)
#define OFF_D0     (OFF_SR + 8192)    // holds demod SUM S (rsqrt in epilogue)
#define OFF_D1     (OFF_D0 + 8192)
#define OFF_B0F    (OFF_D1 + 8192)
#define OFF_B1F    (OFF_B0F + 2048)
#define OFF_NS0F   (OFF_B1F + 2048)
#define OFF_NS1F   (OFF_NS0F + 2048)
#define OFF_RGBBF  (OFF_NS1F + 2048)
#define OFF_WMODR  (OFF_RGBBF + 256)
#define OFF_N0F    (OFF_WMODR + 24576)
#define OFF_N1F    (OFF_N0F + 65536)
#define OFF_WT0    (OFF_N1F + 65536)
#define WT_BYTES   4718592            // 16*3*4*512*3*8*2
#define OFF_WT1    (OFF_WT0 + WT_BYTES)
#define OFF_XP0    (OFF_WT1 + WT_BYTES)
#define XP_BYTES   17842176           // 4*16*4*4356*8*2
#define OFF_XP1    (OFF_XP0 + XP_BYTES)

// ---------------- helpers ----------------
__device__ __forceinline__ float bf2f(unsigned short u) {
  return __uint_as_float(((unsigned int)u) << 16);
}
__device__ __forceinline__ unsigned short f2bf(float f) {
  unsigned int x = __float_as_uint(f);
  unsigned int r = x + 0x7FFFu + ((x >> 16) & 1u);
  return (unsigned short)(r >> 16);
}
__device__ __forceinline__ float ldin(const void* p, long i, int bf) {
  if (bf) return bf2f(((const unsigned short*)p)[i]);
  return ((const float*)p)[i];
}
__device__ __forceinline__ void async_ld16(const void* g, void* l) {
  __builtin_amdgcn_global_load_lds(
      (const __attribute__((address_space(1))) unsigned int*)g,
      (__attribute__((address_space(3))) unsigned int*)l, 16, 0, 0);
}
// bilinear 2x upsample taps (align_corners=False / jax.image.resize, clamped)
__device__ __forceinline__ void upw(int o, int n_in, int& lo, int& hi, float& wlo) {
  int k = o >> 1;
  if (o & 1) { lo = k; hi = k + 1; if (hi > n_in - 1) hi = n_in - 1; wlo = 0.75f; }
  else       { lo = k - 1; if (lo < 0) lo = 0; hi = k; wlo = 0.25f; }
}

// ---------------- K0: dtype flag ----------------
__global__ void k_flag(const unsigned int* msb, int* flag) {
  if (threadIdx.x == 0 && blockIdx.x == 0)
    *flag = (msb[0] == 0x3F803F80u) ? 1 : 0;
}

// ---------------- K0b: zero padding border of all Xp planes -----------------
// rows 0 & 65 (all cols) + cols 0 & 65 (rows 1..64); 260 entries per plane,
// 512 planes (Xp0 and Xp1 contiguous). grid 520 x 256.
__global__ void k_zero(unsigned short* Xp) {
  const int idx = blockIdx.x * 256 + threadIdx.x;  // 0..133119
  const int plane = idx / 260;
  const int rem = idx - plane * 260;
  int row, col;
  if (rem < 132) { row = (rem >= 66) ? 65 : 0; col = (rem >= 66) ? rem - 66 : rem; }
  else { int r2 = rem - 132; col = (r2 >= 64) ? 65 : 0; row = (r2 & 63) + 1; }
  const short8 z = {0, 0, 0, 0, 0, 0, 0, 0};
  *(short8*)&Xp[((long)plane * NPP + row * 66 + col) * 8] = z;
}

// ---------------- K1: styles, one wave per output channel ------------------
__global__ void k_styles(const void* w, const void* msw0, const void* msb0,
                         const void* msw1, const void* msb1,
                         const void* mswr, const void* msbr,
                         float* s0, float* s1, float* sr, const int* flagp) {
  const int bf = *flagp;
  const int mat = blockIdx.x >> 7, chunk = blockIdx.x & 127;
  const int wv = threadIdx.x >> 6, lane = threadIdx.x & 63;
  const int i = chunk * 4 + wv;
  const void* msw; const void* msb; float* out;
  if (mat == 0)      { msw = msw0; msb = msb0; out = s0; }
  else if (mat == 1) { msw = msw1; msb = msb1; out = s1; }
  else               { msw = mswr; msb = msbr; out = sr; }
  float a[4] = {0.f, 0.f, 0.f, 0.f};
  const int n0 = lane * 8;
  if (bf) {
    short8 m8 = *(const short8*)((const unsigned short*)msw + (long)i * 512 + n0);
    for (int b = 0; b < 4; ++b) {
      short8 w8 = *(const short8*)((const unsigned short*)w + b * 512 + n0);
      float s = 0.f;
      for (int e = 0; e < 8; ++e)
        s += bf2f((unsigned short)m8[e]) * bf2f((unsigned short)w8[e]);
      a[b] = s;
    }
  } else {
    const float* mrow = (const float*)msw + (long)i * 512 + n0;
    float4 m0v = *(const float4*)mrow, m1v = *(const float4*)(mrow + 4);
    for (int b = 0; b < 4; ++b) {
      const float* wr = (const float*)w + b * 512 + n0;
      float4 w0v = *(const float4*)wr, w1v = *(const float4*)(wr + 4);
      a[b] = m0v.x * w0v.x + m0v.y * w0v.y + m0v.z * w0v.z + m0v.w * w0v.w +
             m1v.x * w1v.x + m1v.y * w1v.y + m1v.z * w1v.z + m1v.w * w1v.w;
    }
  }
  for (int off = 1; off < 64; off <<= 1)
    for (int b = 0; b < 4; ++b) a[b] += __shfl_xor(a[b], off, 64);
  if (lane == 0) {
    const float mb = ldin(msb, i, bf);
    for (int b = 0; b < 4; ++b) out[b * 512 + i] = a[b] * MS_SCALE_F + mb;
  }
}

// ---------------- K2: convert small vectors/noise to fp32, rgb mod weights --
__global__ void k_convert(const void* b0, const void* b1, const void* nv0, const void* nv1,
                          const void* rb, const void* rw, const void* noise0, const void* noise1,
                          float* ob0, float* ob1, float* ons0, float* ons1, float* orb,
                          float* owmr, float* on0, float* on1,
                          const float* sr, const int* flagp) {
  const int bf = *flagp;
  const int t = blockIdx.x * blockDim.x + threadIdx.x;
  const int stride = gridDim.x * blockDim.x;
  if (t < 512) {
    ob0[t] = ldin(b0, t, bf); ob1[t] = ldin(b1, t, bf);
    ons0[t] = ldin(nv0, t, bf); ons1[t] = ldin(nv1, t, bf);
  }
  if (t < 3) orb[t] = ldin(rb, t, bf);
  for (int i = t; i < 16384; i += stride) {
    on0[i] = ldin(noise0, i, bf);
    on1[i] = ldin(noise1, i, bf);
  }
  for (int i = t; i < 4 * 3 * 512; i += stride) {
    int b = i / 1536; int r = i - b * 1536; int c = r >> 9; int ci = r & 511;
    owmr[i] = RGB_SCALE_F * ldin(rw, c * 512 + ci, bf) * sr[b * 512 + ci];
  }
}

// ---------------- K3: fused weight staging + demod sums ---------------------
// Writes Wt layout [kb 16][ky 3][q 4][co 512][kx 3][j 8].
__global__ void k_wtd(const void* w0, const void* w1, const float* s0, const float* s1,
                      unsigned short* Wt0, unsigned short* Wt1,
                      float* S0, float* S1, const int* flagp) {
  const int bf = *flagp;
  const int l = blockIdx.x >> 9, co = blockIdx.x & 511;
  const void* w = l ? w1 : w0;
  const float* s = l ? s1 : s0;
  unsigned short* Wt = l ? Wt1 : Wt0;
  float* S = l ? S1 : S0;
  float part[4] = {0.f, 0.f, 0.f, 0.f};
  for (int h = 0; h < 2; ++h) {
    const int ci = threadIdx.x + h * 256;
    const int kb = ci >> 5, q = (ci >> 3) & 3, j = ci & 7;
    const long rbase = ((long)co * 512 + ci) * 9;
    float wsq = 0.f;
    for (int t = 0; t < 9; ++t) {
      const int ky = t / 3, kx = t - ky * 3;
      float v = ldin(w, rbase + t, bf);
      wsq += v * v;
      Wt[(((((long)kb * 3 + ky) * 4 + q) * 512 + co) * 3 + kx) * 8 + j] = f2bf(v);
    }
    for (int b = 0; b < 4; ++b) {
      float sv = s[b * 512 + ci];
      part[b] += sv * sv * wsq;
    }
  }
  __shared__ float red[256 * 4];
  for (int b = 0; b < 4; ++b) red[threadIdx.x * 4 + b] = part[b];
  __syncthreads();
  for (int off = 128; off > 0; off >>= 1) {
    if (threadIdx.x < off)
      for (int b = 0; b < 4; ++b)
        red[threadIdx.x * 4 + b] += red[(threadIdx.x + off) * 4 + b];
    __syncthreads();
  }
  if (threadIdx.x < 4) S[threadIdx.x * 512 + co] = red[threadIdx.x];
}

// ---------------- K4: fused upsample*s0 + transpose -> Xp0 ------------------
__global__ void k_upt(const void* maps, const float* s0, unsigned short* Xp0,
                      const int* flagp) {
  const int bf = *flagp;
  const int t = blockIdx.x, kb = blockIdx.y, b = blockIdx.z;
  __shared__ float lds[32][4][32];  // [ci][r][x]
  {
    const int ciq = threadIdx.x >> 5;   // 0..7
    const int x = threadIdx.x & 31;
    for (int cc = 0; cc < 4; ++cc) {
      const int ci = cc * 8 + ciq;
      const long cbase = ((long)(b * 512 + kb * 32 + ci)) << 10;
      for (int r = 0; r < 4; ++r) {
        int ir = 2 * t - 1 + r;
        ir = ir < 0 ? 0 : (ir > 31 ? 31 : ir);
        lds[ci][r][x] = ldin(maps, cbase + ir * 32 + x, bf);
      }
    }
  }
  __syncthreads();
  const int q = threadIdx.x >> 6, px = threadIdx.x & 63;
  int xlo, xhi; float wx;
  upw(px, 32, xlo, xhi, wx);
  float sv[8];
  for (int jj = 0; jj < 8; ++jj) sv[jj] = s0[b * 512 + kb * 32 + q * 8 + jj];
  for (int y = 0; y < 4; ++y) {
    const int yg = 4 * t + y;
    int ylo, yhi; float wy;
    upw(yg, 32, ylo, yhi, wy);
    const int rlo = ylo - (2 * t - 1), rhi = yhi - (2 * t - 1);
    short8 pk;
    for (int jj = 0; jj < 8; ++jj) {
      const int ci = q * 8 + jj;
      float vlo = wx * lds[ci][rlo][xlo] + (1.f - wx) * lds[ci][rlo][xhi];
      float vhi = wx * lds[ci][rhi][xlo] + (1.f - wx) * lds[ci][rhi][xhi];
      float v = (wy * vlo + (1.f - wy) * vhi) * sv[jj];
      pk[jj] = (short)f2bf(v);
    }
    *(short8*)&Xp0[((((long)b * 16 + kb) * 4 + q) * NPP + (yg + 1) * 66 + (px + 1)) * 8] = pk;
  }
}

// ---------------- K6/K7: modulated conv v7 (1 barrier per kb) ---------------
// Block: 128 cout x 128 px (2 rows of 64). Waves 2x2, each 64x64 (4x4 frags).
// LDS: B dbuf [2][row 4][q 4][col 66][8] = 33792 B. A from global with
// immediate offsets off one per-(kb,ky) base. 144 MFMAs per barrier.
#define MFMA16 __builtin_amdgcn_mfma_f32_16x16x32_bf16
template <int LAYER>
__global__ __launch_bounds__(256, 2) void k_conv(
    const unsigned short* __restrict__ Wt,   // [16][3][4][512][3][8]
    const unsigned short* Xp,                // [4][16][4][4356][8]
    const float* __restrict__ Ssum,          // [4][512] demod sum
    const float* __restrict__ bias,          // [512]
    const float* __restrict__ nsc,           // [512] noise strength
    const float* __restrict__ noise,         // [4][4096]
    const float* __restrict__ snext,         // [4][512] next-layer style
    unsigned short* XpOut,                   // LAYER 0: next padded input
    void* dout,                              // LAYER 1: d_out (h at +HOUT_OFF)
    const int* __restrict__ flagp) {
  __shared__ __align__(16) unsigned short Bl[2][4][4][528];  // 33792 B
  const int idx = blockIdx.x;
  const int mt = idx & 3, b = (idx >> 2) & 3, nt = idx >> 4;
  const int m0 = mt << 7, y0 = nt << 1;
  const int lane = threadIdx.x & 63, wv = threadIdx.x >> 6;
  const int wm = wv >> 1, wn = wv & 1;
  const int q = lane >> 4, l15 = lane & 15;

  const floatx4 vz = {0.f, 0.f, 0.f, 0.f};
  floatx4 c00 = vz, c01 = vz, c02 = vz, c03 = vz;
  floatx4 c10 = vz, c11 = vz, c12 = vz, c13 = vz;
  floatx4 c20 = vz, c21 = vz, c22 = vz, c23 = vz;
  floatx4 c30 = vz, c31 = vz, c32 = vz, c33 = vz;

  // A per-lane base (elements): lane covers (q, co=m0+wm*64+i*16+l15, kx, j)
  const unsigned short* Abase = Wt + ((long)(q * 512 + m0 + wm * 64 + l15)) * 24;

  // stage all 4 rows of ci-block kb into buffer bu (full 66 cols, q = wv)
  auto issueB = [&](int kb, int bu) {
    const unsigned short* rowb =
        Xp + ((((long)b * 16 + kb) * 4 + wv) * NPP + (long)y0 * 66) * 8;
#pragma unroll
    for (int r = 0; r < 4; ++r) {
      const unsigned short* src = rowb + (long)r * 66 * 8;
      unsigned short* dst = &Bl[bu][r][wv][0];
      async_ld16(src + (long)lane * 8, dst);                      // cols 0..63
      if (lane < 2) async_ld16(src + (long)(64 + lane) * 8, dst + 512);  // 64,65
    }
  };

  issueB(0, 0);  // prologue

#pragma unroll 1
  for (int kb = 0; kb < 16; ++kb) {
    __syncthreads();                    // B(kb) landed; kb-1 readers done
    issueB((kb + 1) & 15, (kb + 1) & 1);  // prefetch next kb's B
    const int bu = kb & 1;
#pragma unroll 1
    for (int ky = 0; ky < 3; ++ky) {
      const unsigned short* ap = Abase + (long)(kb * 3 + ky) * 49152;
      short8 a_[3][4];
#pragma unroll
      for (int i = 0; i < 4; ++i)
#pragma unroll
        for (int kx = 0; kx < 3; ++kx)
          a_[kx][i] = *(const short8*)(ap + i * 384 + kx * 8);
      const unsigned short* brow = &Bl[bu][wn + ky][q][0];
#define TAPC(KX)                                                               \
  {                                                                            \
    short8 aa0 = a_[KX][0], aa1 = a_[KX][1], aa2 = a_[KX][2], aa3 = a_[KX][3]; \
    short8 bb0 = *(const short8*)&brow[(0 * 16 + l15 + (KX)) * 8];             \
    short8 bb1 = *(const short8*)&brow[(1 * 16 + l15 + (KX)) * 8];             \
    short8 bb2 = *(const short8*)&brow[(2 * 16 + l15 + (KX)) * 8];             \
    short8 bb3 = *(const short8*)&brow[(3 * 16 + l15 + (KX)) * 8];             \
    c00 = MFMA16(aa0, bb0, c00, 0, 0, 0); c01 = MFMA16(aa0, bb1, c01, 0, 0, 0);\
    c02 = MFMA16(aa0, bb2, c02, 0, 0, 0); c03 = MFMA16(aa0, bb3, c03, 0, 0, 0);\
    c10 = MFMA16(aa1, bb0, c10, 0, 0, 0); c11 = MFMA16(aa1, bb1, c11, 0, 0, 0);\
    c12 = MFMA16(aa1, bb2, c12, 0, 0, 0); c13 = MFMA16(aa1, bb3, c13, 0, 0, 0);\
    c20 = MFMA16(aa2, bb0, c20, 0, 0, 0); c21 = MFMA16(aa2, bb1, c21, 0, 0, 0);\
    c22 = MFMA16(aa2, bb2, c22, 0, 0, 0); c23 = MFMA16(aa2, bb3, c23, 0, 0, 0);\
    c30 = MFMA16(aa3, bb0, c30, 0, 0, 0); c31 = MFMA16(aa3, bb1, c31, 0, 0, 0);\
    c32 = MFMA16(aa3, bb2, c32, 0, 0, 0); c33 = MFMA16(aa3, bb3, c33, 0, 0, 0);\
  }
      TAPC(0)
      TAPC(1)
      TAPC(2)
#undef TAPC
    }
  }

  // ---- epilogue: demod(rsqrt), bias, noise, lrelu; write next input or h ---
  floatx4 accv[4][4] = {{c00, c01, c02, c03}, {c10, c11, c12, c13},
                        {c20, c21, c22, c23}, {c30, c31, c32, c33}};
  const int bfflag = *flagp;
  const int coB = m0 + (wm << 6) + ((lane >> 4) << 2);
  const int xB = lane & 15;
  const int y = y0 + wn;
  for (int i = 0; i < 4; ++i) {
    const int co = coB + (i << 4);
    float Ds[4], bi[4], nv[4], sx[4];
    for (int r = 0; r < 4; ++r) {
      float Sv = Ssum[b * 512 + co + r];
      Ds[r] = CONV_SCALE_F * rsqrtf(CONV_SCALE_F * CONV_SCALE_F * Sv + 1e-8f);
      bi[r] = bias[co + r];
      nv[r] = nsc[co + r];
      sx[r] = (LAYER == 0) ? snext[b * 512 + co + r] : 0.f;
    }
    for (int j = 0; j < 4; ++j) {
      const int x = (j << 4) + xB;
      const int p = (y << 6) + x;
      const float nz = noise[b * 4096 + p];
      if (LAYER == 0) {
        unsigned long long pk = 0ull;
        for (int r = 0; r < 4; ++r) {
          float v = accv[i][j][r] * Ds[r] + bi[r] + nv[r] * nz;
          v = (v >= 0.f) ? v : 0.2f * v;
          pk |= (unsigned long long)f2bf(v * sx[r]) << (16 * r);
        }
        const int pp = (y + 1) * 66 + (x + 1);
        const long o = ((((long)b * 16 + (co >> 5)) * 4 + ((co >> 3) & 3)) * NPP + pp) * 8 + (co & 7);
        *(unsigned long long*)(XpOut + o) = pk;
      } else {
        for (int r = 0; r < 4; ++r) {
          float v = accv[i][j][r] * Ds[r] + bi[r] + nv[r] * nz;
          v = (v >= 0.f) ? v : 0.2f * v;
          const long o = (((long)(b * 512 + co + r)) << 12) + p;
          if (bfflag) ((unsigned short*)dout)[HOUT_OFF + o] = f2bf(v);
          else        ((float*)dout)[HOUT_OFF + o] = v;
        }
      }
    }
  }
}

// ---------------- K8: to_rgb (1x1 modconv, no demod) + rgb skip upsample ----
__global__ void k_rgb(const void* rgb_in, const float* wmodr, const float* rgbb,
                      void* dout, const int* flagp) {
  const int bf = *flagp;
  const int b = blockIdx.y, p0 = blockIdx.x * 64;
  const int px = threadIdx.x & 63, g = threadIdx.x >> 6;
  const char* hbytes = (const char*)dout + (long)HOUT_OFF * (bf ? 2 : 4);
  float a0 = 0.f, a1 = 0.f, a2 = 0.f;
  const float* wm = wmodr + b * 1536;
  for (int ci = g * 128; ci < g * 128 + 128; ++ci) {
    const long o = (((long)(b * 512 + ci)) << 12) + p0 + px;
    const float hv = bf ? bf2f(((const unsigned short*)hbytes)[o])
                        : ((const float*)hbytes)[o];
    a0 += wm[ci] * hv;
    a1 += wm[512 + ci] * hv;
    a2 += wm[1024 + ci] * hv;
  }
  __shared__ float red[4][3][64];
  red[g][0][px] = a0; red[g][1][px] = a1; red[g][2][px] = a2;
  __syncthreads();
  if (g == 0) {
    const int p = p0 + px;
    const int y = p >> 6, x = p & 63;
    int ylo, yhi, xlo, xhi; float wy, wx;
    upw(y, 32, ylo, yhi, wy);
    upw(x, 32, xlo, xhi, wx);
    for (int c = 0; c < 3; ++c) {
      float s = red[0][c][px] + red[1][c][px] + red[2][c][px] + red[3][c][px];
      const long base = (long)(b * 3 + c) << 10;
      const float v00 = ldin(rgb_in, base + ylo * 32 + xlo, bf);
      const float v01 = ldin(rgb_in, base + ylo * 32 + xhi, bf);
      const float v10 = ldin(rgb_in, base + yhi * 32 + xlo, bf);
      const float v11 = ldin(rgb_in, base + yhi * 32 + xhi, bf);
      const float up = wy * (wx * v00 + (1.f - wx) * v01) +
                       (1.f - wy) * (wx * v10 + (1.f - wx) * v11);
      const float v = up + s + rgbb[c];
      const long o = ((long)(b * 3 + c) << 12) + p;
      if (bf) ((unsigned short*)dout)[o] = f2bf(v);
      else    ((float*)dout)[o] = v;
    }
  }
}

// ---------------------------------------------------------------------------
extern "C" void kernel_launch(void* const* d_in, const int* in_sizes, int n_in,
                              void* d_out, int out_size, void* d_ws, size_t ws_size,
                              hipStream_t stream) {
  char* ws = (char*)d_ws;
  int* flag = (int*)(ws + OFF_FLAG);
  float* s0 = (float*)(ws + OFF_S0);
  float* s1 = (float*)(ws + OFF_S1);
  float* sr = (float*)(ws + OFF_SR);
  float* S0 = (float*)(ws + OFF_D0);
  float* S1 = (float*)(ws + OFF_D1);
  float* b0f = (float*)(ws + OFF_B0F);
  float* b1f = (float*)(ws + OFF_B1F);
  float* ns0f = (float*)(ws + OFF_NS0F);
  float* ns1f = (float*)(ws + OFF_NS1F);
  float* rgbbf = (float*)(ws + OFF_RGBBF);
  float* wmodr = (float*)(ws + OFF_WMODR);
  float* n0f = (float*)(ws + OFF_N0F);
  float* n1f = (float*)(ws + OFF_N1F);
  unsigned short* Wt0 = (unsigned short*)(ws + OFF_WT0);
  unsigned short* Wt1 = (unsigned short*)(ws + OFF_WT1);
  unsigned short* Xp0 = (unsigned short*)(ws + OFF_XP0);
  unsigned short* Xp1 = (unsigned short*)(ws + OFF_XP1);

  // d_in: 0 maps, 1 w, 2 rgb, 3 noise0, 4 noise1, 5 conv0_w, 6 conv0_b,
  // 7 ms0_w, 8 ms0_b, 9 ns0, 10 conv1_w, 11 conv1_b, 12 ms1_w, 13 ms1_b,
  // 14 ns1, 15 rgb_w, 16 rgb_b, 17 msr_w, 18 msr_b
  k_flag<<<1, 64, 0, stream>>>((const unsigned int*)d_in[8], flag);
  k_zero<<<520, 256, 0, stream>>>(Xp0);  // pad borders of Xp0 AND Xp1
  k_styles<<<384, 256, 0, stream>>>(d_in[1], d_in[7], d_in[8], d_in[12], d_in[13],
                                    d_in[17], d_in[18], s0, s1, sr, flag);
  k_convert<<<64, 256, 0, stream>>>(d_in[6], d_in[11], d_in[9], d_in[14], d_in[16],
                                    d_in[15], d_in[3], d_in[4], b0f, b1f, ns0f, ns1f,
                                    rgbbf, wmodr, n0f, n1f, sr, flag);
  k_wtd<<<1024, 256, 0, stream>>>(d_in[5], d_in[10], s0, s1, Wt0, Wt1, S0, S1, flag);
  k_upt<<<dim3(16, 16, 4), 256, 0, stream>>>(d_in[0], s0, Xp0, flag);
  k_conv<0><<<512, 256, 0, stream>>>(Wt0, Xp0, S0, b0f, ns0f, n0f, s1, Xp1,
                                     d_out, flag);
  k_conv<1><<<512, 256, 0, stream>>>(Wt1, Xp1, S1, b1f, ns1f, n1f, s1, Xp1,
                                     d_out, flag);
  k_rgb<<<dim3(64, 4), 256, 0, stream>>>(d_in[2], wmodr, rgbbf, d_out, flag);
  (void)in_sizes; (void)n_in; (void)out_size; (void)ws_size;
}